// Round 11
// baseline (104.823 us; speedup 1.0000x reference)
//
#include <hip/hip_runtime.h>
#include <math.h>

#define TT 1024
#define NN 64
#define CC 128
#define SS 128
#define CH 32          // steps per chunk
#define NCHUNK 32      // chunks covering t = 1..1024
#define NC (NN * CC)   // floats between time rows

typedef float f4 __attribute__((ext_vector_type(4)));

// DPP controls (gfx9/CDNA encodings)
#define DPP_QP_XOR1   0xB1
#define DPP_QP_XOR2   0x4E
#define DPP_WAVE_SHR1 0x138
#define DPP_ROW_MIRR  0x140
#define DPP_HALF_MIRR 0x141
#define DPP_BCAST15   0x142
#define DPP_BCAST31   0x143

template <int CTRL>
__device__ __forceinline__ float dpp_max_stage(float v) {
    int p = __builtin_amdgcn_update_dpp(__float_as_int(v), __float_as_int(v),
                                        CTRL, 0xF, 0xF, false);
    return fmaxf(v, __int_as_float(p));
}
__device__ __forceinline__ float dpp_shr1(float v) {
    int p = __builtin_amdgcn_update_dpp(0, __float_as_int(v),
                                        DPP_WAVE_SHR1, 0xF, 0xF, true);
    return __int_as_float(p);
}

// inline-asm LDS read: cannot be rematerialized/sunk by the compiler
#define DSR(dst, addr, off) \
    asm volatile("ds_read_b128 %0, %1 offset:" #off : "=v"(dst) : "v"(addr))
#define LGKM(n) do { \
    asm volatile("s_waitcnt lgkmcnt(" #n ")" ::: "memory"); \
    __builtin_amdgcn_sched_barrier(0); } while (0)
#define VMC(n) do { \
    asm volatile("s_waitcnt vmcnt(" #n ")" ::: "memory"); \
    __builtin_amdgcn_sched_barrier(0); } while (0)
#define ISSUE(mi, oea, oeb, opq) do { \
    DSR(gea[mi], base_e, oea); DSR(geb[mi], base_e, oeb); \
    DSR(gpq[mi], base_pq, opq); } while (0)
#define BARRIER() asm volatile("s_barrier" ::: "memory")

// ---------------------------------------------------------------------------
// Main kernel: byte-identical to the verified round-9 kernel (71.5 us).
__global__ __launch_bounds__(320, 1) void ctc_scan(
    const float* __restrict__ lp,        // [T, N, C] fp32 log-softmax
    const int*   __restrict__ targets,   // [N, S]
    const int*   __restrict__ ilen,      // [N]
    const int*   __restrict__ tlen,      // [N]
    float*       __restrict__ v_out)     // [N] terminal log-alpha
{
    const int n    = blockIdx.x;
    const int tid  = threadIdx.x;
    const int wv   = tid >> 6;           // 0 = consumer, 1..4 = producers
    const int lane = tid & 63;

    __shared__ float  s_rows[2][CH][CC];    // 32 KiB: staged lp rows
    __shared__ float4 s_e[2][CH / 2][64];   // 32 KiB: packed emissions
    __shared__ float4 s_pb4[2][CH / 4];     // 256 B:  blank probs

    const int tgA = targets[n * SS + 2 * lane];
    const int tgB = targets[n * SS + 2 * lane + 1];
    const float* lpn = lp + (size_t)n * CC;

    const int w  = wv - 1;
    const int r0 = w * 8;

    auto issue_rows = [&](int c, int buf) {
#pragma unroll
        for (int i = 0; i < 4; ++i) {
            const int r = r0 + 2 * i;
            int t = 1 + c * CH + r + (lane >> 5);
            if (t > TT - 1) t = TT - 1;
            const float* src = lpn + (size_t)t * NC + (lane & 31) * 4;
            __builtin_amdgcn_global_load_lds(
                (const __attribute__((address_space(1))) void*)src,
                (__attribute__((address_space(3))) void*)&s_rows[buf][r][0],
                16, 0, 0);
        }
    };
    auto gather = [&](int buf, int ebuf) {
#pragma unroll
        for (int i = 0; i < 4; ++i) {
            const int rA = r0 + 2 * i, rB = rA + 1;
            const float pa0 = s_rows[buf][rA][tgA], pc0 = s_rows[buf][rA][tgB];
            const float pa1 = s_rows[buf][rB][tgA], pc1 = s_rows[buf][rB][tgB];
            s_e[ebuf][(r0 >> 1) + i][lane] =
                make_float4(__expf(pa0), __expf(pc0), __expf(pa1), __expf(pc1));
        }
        if (lane < 8) {
            const float pbv = s_rows[buf][r0 + lane][0];
            ((float*)s_pb4[ebuf])[r0 + lane] = __expf(pbv);
        }
    };

    if (wv != 0) {
        issue_rows(0, 0);
        issue_rows(1, 1);
        VMC(4);
        gather(0, 0);
    }

    const int tgBm = (lane > 0) ? targets[n * SS + 2 * lane - 1] : -1;
    const float k1f = (lane > 0 && tgA != tgBm) ? 1.f : 0.f;
    const float k3f = (tgB != tgA) ? 1.f : 0.f;
    const int il    = ilen[n];
    const int vs    = 2 * tlen[n] - 1;
    const int vlane = vs >> 2;

    float a0 = 1.f, a1 = 1.f, a2 = 1.f, a3 = 1.f, ls = 0.f;
    if (wv == 0) {
        a0 = (lane == 0) ? __expf(lpn[0])   : 1.f;
        a1 = (lane == 0) ? __expf(lpn[tgA]) : 1.f;
    }
    float a3p = (lane == 0) ? 0.f : 1.f;
    float mr = 1.f, inv = 1.f;

    const unsigned base_e0  = (unsigned)(size_t)(void*)&s_e[0][0][lane];
    const unsigned base_pq0 = (unsigned)(size_t)(void*)&s_pb4[0][0];

    __syncthreads();

    for (int cc = 0; cc < NCHUNK; ++cc) {
        const int b = cc & 1;
        if (wv == 0) {
            const int t0 = 1 + cc * CH;
            const bool cap = ((unsigned)(il - 1 - t0) < (unsigned)CH);
            const unsigned base_e  = base_e0  + (unsigned)(b << 14);
            const unsigned base_pq = base_pq0 + (unsigned)(b << 7);

            f4 gea[3], geb[3], gpq[3];

            auto group4 = [&](const f4& ea, const f4& eb, const f4& pq, int jbase) {
#pragma unroll
                for (int c = 0; c < 4; ++c) {
                    const int j = jbase + c;
                    const float cpa = (c==0)?ea[0]:(c==1)?ea[2]:(c==2)?eb[0]:eb[2];
                    const float cpc = (c==0)?ea[1]:(c==1)?ea[3]:(c==2)?eb[1]:eb[3];
                    const float cpb = pq[c];

                    float nb3 = fmaf(k3f, a1, a3 + a2) * cpc;
                    float a3pn = dpp_shr1(nb3);
                    float nb0 = (a0 + a3p) * cpb;
                    float nb1 = fmaf(k1f, a3p, a0 + a1) * cpa;
                    float nb2 = (a2 + a1) * cpb;

                    const int jj = j & 7;
                    if      (jj == 0) mr = fmaxf(fmaxf(nb0, nb1), fmaxf(nb2, nb3));
                    else if (jj == 1) mr = dpp_max_stage<DPP_QP_XOR1>(mr);
                    else if (jj == 2) mr = dpp_max_stage<DPP_QP_XOR2>(mr);
                    else if (jj == 3) mr = dpp_max_stage<DPP_HALF_MIRR>(mr);
                    else if (jj == 4) mr = dpp_max_stage<DPP_ROW_MIRR>(mr);
                    else if (jj == 5) mr = dpp_max_stage<DPP_BCAST15>(mr);
                    else if (jj == 6) mr = dpp_max_stage<DPP_BCAST31>(mr);
                    else {
                        const float mru = __int_as_float(
                            __builtin_amdgcn_readlane(__float_as_int(mr), 63));
                        inv = 1.0f / mru;
                        ls += __logf(mru);
                        nb0 *= inv; nb1 *= inv; nb2 *= inv; nb3 *= inv;
                    }

                    if (cap) {
                        const int t = t0 + j;
                        if (t == il - 1 && lane == vlane)
                            v_out[n] = __logf((vs & 2) ? nb3 : nb1) + ls;
                    }

                    a0 = nb0; a1 = nb1; a2 = nb2; a3 = nb3;
                    if (jj == 7) a3pn *= inv;
                    a3p = a3pn;
                }
            };

            ISSUE(0, 0,     1024,  0);
            ISSUE(1, 2048,  3072,  16);
            ISSUE(2, 4096,  5120,  32);  LGKM(6); group4(gea[0], geb[0], gpq[0], 0);
            ISSUE(0, 6144,  7168,  48);  LGKM(6); group4(gea[1], geb[1], gpq[1], 4);
            ISSUE(1, 8192,  9216,  64);  LGKM(6); group4(gea[2], geb[2], gpq[2], 8);
            ISSUE(2, 10240, 11264, 80);  LGKM(6); group4(gea[0], geb[0], gpq[0], 12);
            ISSUE(0, 12288, 13312, 96);  LGKM(6); group4(gea[1], geb[1], gpq[1], 16);
            ISSUE(1, 14336, 15360, 112); LGKM(6); group4(gea[2], geb[2], gpq[2], 20);
                                         LGKM(3); group4(gea[0], geb[0], gpq[0], 24);
                                         LGKM(0); group4(gea[1], geb[1], gpq[1], 28);
        } else {
            issue_rows(cc + 2, cc & 1);
            VMC(4);
            if (cc + 1 < NCHUNK) gather((cc + 1) & 1, (cc + 1) & 1);
            asm volatile("s_waitcnt lgkmcnt(0)" ::: "memory");
        }
        BARRIER();
    }
}

// ---------------------------------------------------------------------------
// PROBE: pure register replica of the consumer's per-step chain. One wave per
// block, 64 blocks, no LDS, no barriers, no memory in the loop. Measures the
// serial-chain floor on this HW; result -> ws tail (DCE-proof), own rocprof row.
__global__ __launch_bounds__(64) void ctc_probe(
    const float* __restrict__ seed, float* __restrict__ out)
{
    const int n    = blockIdx.x;
    const int lane = threadIdx.x;

    // un-foldable, well-behaved inputs in [0.5, 1.0)
    float s = seed[n];
    s = s - floorf(s);
    const float cpa = 0.5f + 0.49f * s;
    const float cpb = 0.5f + 0.25f * s;
    const float cpc = 0.99f - 0.30f * s;
    const float k1f = (lane & 1) ? 1.f : 0.f;
    const float k3f = (lane & 2) ? 1.f : 0.f;
    asm volatile("" :: "v"(cpa), "v"(cpb), "v"(cpc));

    float a0 = 1.f, a1 = 1.f, a2 = 1.f, a3 = 1.f, ls = 0.f;
    float a3p = (lane == 0) ? 0.f : 1.f;
    float mr = 1.f, inv = 1.f;

    for (int cc = 0; cc < NCHUNK; ++cc) {
#pragma unroll
        for (int j = 0; j < CH; ++j) {
            float nb3 = fmaf(k3f, a1, a3 + a2) * cpc;
            float a3pn = dpp_shr1(nb3);
            float nb0 = (a0 + a3p) * cpb;
            float nb1 = fmaf(k1f, a3p, a0 + a1) * cpa;
            float nb2 = (a2 + a1) * cpb;

            const int jj = j & 7;
            if      (jj == 0) mr = fmaxf(fmaxf(nb0, nb1), fmaxf(nb2, nb3));
            else if (jj == 1) mr = dpp_max_stage<DPP_QP_XOR1>(mr);
            else if (jj == 2) mr = dpp_max_stage<DPP_QP_XOR2>(mr);
            else if (jj == 3) mr = dpp_max_stage<DPP_HALF_MIRR>(mr);
            else if (jj == 4) mr = dpp_max_stage<DPP_ROW_MIRR>(mr);
            else if (jj == 5) mr = dpp_max_stage<DPP_BCAST15>(mr);
            else if (jj == 6) mr = dpp_max_stage<DPP_BCAST31>(mr);
            else {
                const float mru = __int_as_float(
                    __builtin_amdgcn_readlane(__float_as_int(mr), 63));
                inv = 1.0f / mru;
                ls += __logf(mru);
                nb0 *= inv; nb1 *= inv; nb2 *= inv; nb3 *= inv;
            }

            a0 = nb0; a1 = nb1; a2 = nb2; a3 = nb3;
            if (jj == 7) a3pn *= inv;
            a3p = a3pn;
        }
    }
    if (lane == 0) out[n] = a0 + a1 + a2 + a3 + ls;
}

// loss = -logsumexp(v) over the 64 batch elements; single wave
__global__ void ctc_reduce(const float* __restrict__ v, float* __restrict__ out)
{
    const int lane = threadIdx.x;
    float x = v[lane];
    float m = x;
#pragma unroll
    for (int off = 32; off > 0; off >>= 1) m = fmaxf(m, __shfl_xor(m, off));
    float e = __expf(x - m);
#pragma unroll
    for (int off = 32; off > 0; off >>= 1) e += __shfl_xor(e, off);
    if (lane == 0) out[0] = -(m + __logf(e));
}

extern "C" void kernel_launch(void* const* d_in, const int* in_sizes, int n_in,
                              void* d_out, int out_size, void* d_ws, size_t ws_size,
                              hipStream_t stream) {
    const float* lp      = (const float*)d_in[0];
    const int*   targets = (const int*)d_in[1];
    const int*   ilen    = (const int*)d_in[2];
    const int*   tlen    = (const int*)d_in[3];

    float* v   = (float*)d_ws;              // 64 floats of scratch
    float* pw  = (float*)d_ws + 128;        // probe output (ws tail)
    float* out = (float*)d_out;

    ctc_scan<<<NN, 320, 0, stream>>>(lp, targets, ilen, tlen, v);
    ctc_reduce<<<1, 64, 0, stream>>>(v, out);
    ctc_probe<<<NN, 64, 0, stream>>>(v, pw);   // instrumentation dispatch
}

// Round 12
// 72.012 us; speedup vs baseline: 1.4556x; 1.4556x over previous
//
#include <hip/hip_runtime.h>
#include <math.h>

#define TT 1024
#define NN 64
#define CC 128
#define SS 128
#define CH 32          // steps per chunk
#define NCHUNK 32      // chunks covering t = 1..1024
#define NC (NN * CC)   // floats between time rows

typedef float f4 __attribute__((ext_vector_type(4)));

// DPP controls (gfx9/CDNA encodings)
#define DPP_QP_XOR1   0xB1
#define DPP_QP_XOR2   0x4E
#define DPP_WAVE_SHR1 0x138
#define DPP_ROW_MIRR  0x140
#define DPP_HALF_MIRR 0x141
#define DPP_BCAST15   0x142
#define DPP_BCAST31   0x143

template <int CTRL>
__device__ __forceinline__ float dpp_max_stage(float v) {
    int p = __builtin_amdgcn_update_dpp(__float_as_int(v), __float_as_int(v),
                                        CTRL, 0xF, 0xF, false);
    return fmaxf(v, __int_as_float(p));
}
__device__ __forceinline__ float dpp_shr1(float v) {
    int p = __builtin_amdgcn_update_dpp(0, __float_as_int(v),
                                        DPP_WAVE_SHR1, 0xF, 0xF, true);
    return __int_as_float(p);
}

// inline-asm LDS read: cannot be rematerialized/sunk by the compiler
#define DSR(dst, addr, off) \
    asm volatile("ds_read_b128 %0, %1 offset:" #off : "=v"(dst) : "v"(addr))
#define LGKM(n) do { \
    asm volatile("s_waitcnt lgkmcnt(" #n ")" ::: "memory"); \
    __builtin_amdgcn_sched_barrier(0); } while (0)
#define VMC(n) do { \
    asm volatile("s_waitcnt vmcnt(" #n ")" ::: "memory"); \
    __builtin_amdgcn_sched_barrier(0); } while (0)
#define ISSUE(mi, oea, oeb, opq) do { \
    DSR(gea[mi], base_e, oea); DSR(geb[mi], base_e, oeb); \
    DSR(gpq[mi], base_pq, opq); } while (0)
#define BARRIER() asm volatile("s_barrier" ::: "memory")

// Fused producer/consumer CTC forward scan. One block per batch element n.
// 4 waves -- one per SIMD, so the serial consumer NEVER shares issue slots:
//   wave 0 = consumer (serial recurrence, s_setprio(1), verified asm pipeline)
//   waves 1-3 = producers (stage rows coalesced via global_load_lds, gather
//   targets from LDS, exp, pack into s_e; pair k handled by wave 1+(k%3)).
// Math byte-identical to the verified round-9 kernel (absmax 0).
__global__ __launch_bounds__(256, 1) void ctc_scan(
    const float* __restrict__ lp,        // [T, N, C] fp32 log-softmax
    const int*   __restrict__ targets,   // [N, S]
    const int*   __restrict__ ilen,      // [N]
    const int*   __restrict__ tlen,      // [N]
    float*       __restrict__ v_out)     // [N] terminal log-alpha
{
    const int n    = blockIdx.x;
    const int tid  = threadIdx.x;
    const int wv   = tid >> 6;           // 0 = consumer, 1..3 = producers
    const int lane = tid & 63;

    __shared__ float  s_rows[2][CH][CC];    // 32 KiB: staged lp rows
    __shared__ float4 s_e[2][CH / 2][64];   // 32 KiB: packed emissions
    __shared__ float4 s_pb4[2][CH / 4];     // 256 B:  blank probs

    const int tgA = targets[n * SS + 2 * lane];
    const int tgB = targets[n * SS + 2 * lane + 1];
    const float* lpn = lp + (size_t)n * CC;

    const int w = wv - 1;                // producer index 0..2 (wv!=0)

    // stage instrs i = w, w+3, ... < 16; instr i loads rows 2i, 2i+1 (1 KiB)
    auto issue_rows = [&](int c, int buf) {
#pragma unroll
        for (int i = 0; i < 6; ++i) {
            const int idx = 3 * i + w;
            if (idx < 16) {
                const int r = 2 * idx;
                int t = 1 + c * CH + r + (lane >> 5);
                if (t > TT - 1) t = TT - 1;
                const float* src = lpn + (size_t)t * NC + (lane & 31) * 4;
                __builtin_amdgcn_global_load_lds(
                    (const __attribute__((address_space(1))) void*)src,
                    (__attribute__((address_space(3))) void*)&s_rows[buf][r][0],
                    16, 0, 0);
            }
        }
    };
    // gather+exp+pack pairs k = w, w+3, ... < 16; w==2 also does blanks
    auto gather = [&](int buf, int ebuf) {
#pragma unroll
        for (int i = 0; i < 6; ++i) {
            const int k = 3 * i + w;
            if (k < 16) {
                const int rA = 2 * k, rB = rA + 1;
                const float pa0 = s_rows[buf][rA][tgA], pc0 = s_rows[buf][rA][tgB];
                const float pa1 = s_rows[buf][rB][tgA], pc1 = s_rows[buf][rB][tgB];
                s_e[ebuf][k][lane] =
                    make_float4(__expf(pa0), __expf(pc0), __expf(pa1), __expf(pc1));
            }
        }
        if (w == 2 && lane < CH) {
            const float pbv = s_rows[buf][lane][0];
            ((float*)s_pb4[ebuf])[lane] = __expf(pbv);
        }
    };

    if (wv != 0) {
        issue_rows(0, 0);
        issue_rows(1, 1);
        if (w == 0) { VMC(6); } else { VMC(5); }   // chunk-0 rows complete
        gather(0, 0);
    }

    const int tgBm = (lane > 0) ? targets[n * SS + 2 * lane - 1] : -1;
    const float k1f = (lane > 0 && tgA != tgBm) ? 1.f : 0.f;
    const float k3f = (tgB != tgA) ? 1.f : 0.f;
    const int il    = ilen[n];
    const int vs    = 2 * tlen[n] - 1;
    const int vlane = vs >> 2;

    float a0 = 1.f, a1 = 1.f, a2 = 1.f, a3 = 1.f, ls = 0.f;
    if (wv == 0) {
        a0 = (lane == 0) ? __expf(lpn[0])   : 1.f;
        a1 = (lane == 0) ? __expf(lpn[tgA]) : 1.f;
    }
    float a3p = (lane == 0) ? 0.f : 1.f;
    float mr = 1.f, inv = 1.f;

    const unsigned base_e0  = (unsigned)(size_t)(void*)&s_e[0][0][lane];
    const unsigned base_pq0 = (unsigned)(size_t)(void*)&s_pb4[0][0];

    __syncthreads();   // prologue barrier (one-time full drain -- fine)

    if (wv == 0) __builtin_amdgcn_s_setprio(1);   // serial wave wins arbitration

    for (int cc = 0; cc < NCHUNK; ++cc) {
        const int b = cc & 1;
        if (wv == 0) {
            const int t0 = 1 + cc * CH;
            const bool cap = ((unsigned)(il - 1 - t0) < (unsigned)CH);
            const unsigned base_e  = base_e0  + (unsigned)(b << 14);
            const unsigned base_pq = base_pq0 + (unsigned)(b << 7);

            f4 gea[3], geb[3], gpq[3];

            auto group4 = [&](const f4& ea, const f4& eb, const f4& pq, int jbase) {
#pragma unroll
                for (int c = 0; c < 4; ++c) {
                    const int j = jbase + c;
                    const float cpa = (c==0)?ea[0]:(c==1)?ea[2]:(c==2)?eb[0]:eb[2];
                    const float cpc = (c==0)?ea[1]:(c==1)?ea[3]:(c==2)?eb[1]:eb[3];
                    const float cpb = pq[c];

                    float nb3 = fmaf(k3f, a1, a3 + a2) * cpc;
                    float a3pn = dpp_shr1(nb3);
                    float nb0 = (a0 + a3p) * cpb;
                    float nb1 = fmaf(k1f, a3p, a0 + a1) * cpa;
                    float nb2 = (a2 + a1) * cpb;

                    const int jj = j & 7;
                    if      (jj == 0) mr = fmaxf(fmaxf(nb0, nb1), fmaxf(nb2, nb3));
                    else if (jj == 1) mr = dpp_max_stage<DPP_QP_XOR1>(mr);
                    else if (jj == 2) mr = dpp_max_stage<DPP_QP_XOR2>(mr);
                    else if (jj == 3) mr = dpp_max_stage<DPP_HALF_MIRR>(mr);
                    else if (jj == 4) mr = dpp_max_stage<DPP_ROW_MIRR>(mr);
                    else if (jj == 5) mr = dpp_max_stage<DPP_BCAST15>(mr);
                    else if (jj == 6) mr = dpp_max_stage<DPP_BCAST31>(mr);
                    else {
                        const float mru = __int_as_float(
                            __builtin_amdgcn_readlane(__float_as_int(mr), 63));
                        inv = 1.0f / mru;
                        ls += __logf(mru);
                        nb0 *= inv; nb1 *= inv; nb2 *= inv; nb3 *= inv;
                    }

                    if (cap) {
                        const int t = t0 + j;
                        if (t == il - 1 && lane == vlane)
                            v_out[n] = __logf((vs & 2) ? nb3 : nb1) + ls;
                    }

                    a0 = nb0; a1 = nb1; a2 = nb2; a3 = nb3;
                    if (jj == 7) a3pn *= inv;
                    a3p = a3pn;
                }
            };

            ISSUE(0, 0,     1024,  0);
            ISSUE(1, 2048,  3072,  16);
            ISSUE(2, 4096,  5120,  32);  LGKM(6); group4(gea[0], geb[0], gpq[0], 0);
            ISSUE(0, 6144,  7168,  48);  LGKM(6); group4(gea[1], geb[1], gpq[1], 4);
            ISSUE(1, 8192,  9216,  64);  LGKM(6); group4(gea[2], geb[2], gpq[2], 8);
            ISSUE(2, 10240, 11264, 80);  LGKM(6); group4(gea[0], geb[0], gpq[0], 12);
            ISSUE(0, 12288, 13312, 96);  LGKM(6); group4(gea[1], geb[1], gpq[1], 16);
            ISSUE(1, 14336, 15360, 112); LGKM(6); group4(gea[2], geb[2], gpq[2], 20);
                                         LGKM(3); group4(gea[0], geb[0], gpq[0], 24);
                                         LGKM(0); group4(gea[1], geb[1], gpq[1], 28);
        } else {
            issue_rows(cc + 2, cc & 1);
            if (w == 0) { VMC(6); } else { VMC(5); }   // chunk cc+1 rows done
            if (cc + 1 < NCHUNK) gather((cc + 1) & 1, (cc + 1) & 1);
            asm volatile("s_waitcnt lgkmcnt(0)" ::: "memory");
        }
        BARRIER();
    }
}

// loss = -logsumexp(v) over the 64 batch elements; single wave
__global__ void ctc_reduce(const float* __restrict__ v, float* __restrict__ out)
{
    const int lane = threadIdx.x;
    float x = v[lane];
    float m = x;
#pragma unroll
    for (int off = 32; off > 0; off >>= 1) m = fmaxf(m, __shfl_xor(m, off));
    float e = __expf(x - m);
#pragma unroll
    for (int off = 32; off > 0; off >>= 1) e += __shfl_xor(e, off);
    if (lane == 0) out[0] = -(m + __logf(e));
}

extern "C" void kernel_launch(void* const* d_in, const int* in_sizes, int n_in,
                              void* d_out, int out_size, void* d_ws, size_t ws_size,
                              hipStream_t stream) {
    const float* lp      = (const float*)d_in[0];
    const int*   targets = (const int*)d_in[1];
    const int*   ilen    = (const int*)d_in[2];
    const int*   tlen    = (const int*)d_in[3];

    float* v   = (float*)d_ws;    // 64 floats of scratch
    float* out = (float*)d_out;

    ctc_scan<<<NN, 256, 0, stream>>>(lp, targets, ilen, tlen, v);
    ctc_reduce<<<1, 64, 0, stream>>>(v, out);
}